// Round 1
// baseline (7365.727 us; speedup 1.0000x reference)
//
#include <hip/hip_runtime.h>
#include <math.h>

#define NA 10000      // atoms
#define NE 160000     // edges
#define NG 100        // graphs
#define DF 128
#define NL 5

__device__ __forceinline__ float silu_f(float x) {
    return x / (1.0f + __expf(-x));
}

__device__ __forceinline__ void sph9(float dx, float dy, float dz, float* s) {
    float r = sqrtf(dx * dx + dy * dy + dz * dz);
    float inv = 1.0f / fmaxf(r, 1e-12f);
    float x = dx * inv, y = dy * inv, z = dz * inv;
    const float S3 = 1.7320508075688772f;
    s[0] = 1.0f;
    s[1] = x; s[2] = y; s[3] = z;
    s[4] = S3 * x * z;
    s[5] = S3 * x * y;
    s[6] = y * y - 0.5f * (x * x + z * z);
    s[7] = S3 * y * z;
    s[8] = 0.5f * S3 * (z * z - x * x);
}

// ---------------- GEMM: C(M x 128) = act(A(M x K) @ W(K x 128) + b) ----------
// MODE 0: plain A (lda = K)
// MODE 1: edge A = [feat[row](128), feat[col](128), d2, ip(3)]   K=260
// MODE 2: edge A = [dist, feat[row](128), feat[col](128)]        K=257
template <int MODE, bool ACT>
__global__ __launch_bounds__(256) void gemm_fused(
    const float* __restrict__ A, int M, int K,
    const float* __restrict__ W, const float* __restrict__ bias,
    float* __restrict__ C,
    const int* __restrict__ row, const int* __restrict__ colI,
    const float* __restrict__ feat,
    const float* __restrict__ extra, const float* __restrict__ ip)
{
    __shared__ float As[16][132];  // [kc][m], padded row stride (132*4 % 16 == 0)
    __shared__ float Bs[16][128];  // [kc][n]

    const int tid = threadIdx.x;
    const int m0 = blockIdx.x * 128;
    const int tx = tid & 15;   // 0..15 -> col groups
    const int ty = tid >> 4;   // 0..15 -> row groups

    float acc[8][8];
#pragma unroll
    for (int i = 0; i < 8; i++)
#pragma unroll
        for (int j = 0; j < 8; j++) acc[i][j] = 0.0f;

    for (int k0 = 0; k0 < K; k0 += 16) {
        // ---- load A tile (128 rows x 16 k) ----
#pragma unroll
        for (int i = 0; i < 8; i++) {
            int flat = tid + i * 256;
            int r = flat >> 4;
            int c = flat & 15;
            int e = m0 + r;
            int k = k0 + c;
            float v = 0.0f;
            if (e < M && k < K) {
                if (MODE == 0) {
                    v = A[(size_t)e * K + k];
                } else if (MODE == 1) {
                    if (k < 128)       v = feat[(size_t)row[e] * DF + k];
                    else if (k < 256)  v = feat[(size_t)colI[e] * DF + (k - 128)];
                    else if (k == 256) v = extra[e];
                    else               v = ip[(size_t)e * 3 + (k - 257)];
                } else {  // MODE 2
                    if (k == 0)        v = extra[e];
                    else if (k < 129)  v = feat[(size_t)row[e] * DF + (k - 1)];
                    else               v = feat[(size_t)colI[e] * DF + (k - 129)];
                }
            }
            As[c][r] = v;
        }
        // ---- load B tile (16 k x 128 n) ----
#pragma unroll
        for (int i = 0; i < 8; i++) {
            int flat = tid + i * 256;
            int kr = flat >> 7;
            int c = flat & 127;
            int k = k0 + kr;
            Bs[kr][c] = (k < K) ? W[(size_t)k * DF + c] : 0.0f;
        }
        __syncthreads();

#pragma unroll
        for (int kk = 0; kk < 16; kk++) {
            float a[8], b[8];
            *(float4*)&a[0] = *(const float4*)&As[kk][ty * 4];
            *(float4*)&a[4] = *(const float4*)&As[kk][64 + ty * 4];
            *(float4*)&b[0] = *(const float4*)&Bs[kk][tx * 4];
            *(float4*)&b[4] = *(const float4*)&Bs[kk][64 + tx * 4];
#pragma unroll
            for (int i = 0; i < 8; i++)
#pragma unroll
                for (int j = 0; j < 8; j++) acc[i][j] += a[i] * b[j];
        }
        __syncthreads();
    }

    // ---- epilogue ----
#pragma unroll
    for (int i = 0; i < 8; i++) {
        int r = (i < 4) ? (ty * 4 + i) : (64 + ty * 4 + (i - 4));
        int e = m0 + r;
        if (e >= M) continue;
#pragma unroll
        for (int j = 0; j < 8; j++) {
            int c = (j < 4) ? (tx * 4 + j) : (64 + tx * 4 + (j - 4));
            float v = acc[i][j] + bias[c];
            if (ACT) v = silu_f(v);
            C[(size_t)e * DF + c] = v;
        }
    }
}

// ---------------- small output layer: out(M x NO) = H(M x 128) @ W2 + b2 -----
template <int NO>
__global__ __launch_bounds__(256) void mlp_out_small(
    const float* __restrict__ H, const float* __restrict__ W2,
    const float* __restrict__ b2, float* __restrict__ out, int M)
{
    __shared__ float Ws[128 * NO];
    int tid = threadIdx.x;
    for (int i = tid; i < 128 * NO; i += 256) Ws[i] = W2[i];
    __syncthreads();
    int wave = tid >> 6;
    int lane = tid & 63;
    int m = blockIdx.x * 4 + wave;
    if (m >= M) return;
    float h0 = H[(size_t)m * DF + lane];
    float h1 = H[(size_t)m * DF + 64 + lane];
#pragma unroll
    for (int j = 0; j < NO; j++) {
        float s = h0 * Ws[lane * NO + j] + h1 * Ws[(64 + lane) * NO + j];
#pragma unroll
        for (int off = 32; off > 0; off >>= 1) s += __shfl_down(s, off, 64);
        if (lane == 0) out[(size_t)m * NO + j] = s + b2[j];
    }
}

// ---------------- misc small kernels ----------------------------------------
__global__ void k_init_feat(const int* __restrict__ atoms,
                            const float* __restrict__ emb,
                            float* __restrict__ feat) {
    int idx = blockIdx.x * blockDim.x + threadIdx.x;
    if (idx < NA * DF) feat[idx] = emb[atoms[idx >> 7] * DF + (idx & 127)];
}

__global__ void k_copy_pos(const float* __restrict__ pos, float* __restrict__ posc) {
    int idx = blockIdx.x * blockDim.x + threadIdx.x;
    if (idx < NA * 3) posc[idx] = pos[idx];
}

__global__ void k_batch_stats(const float* __restrict__ pos, const int* __restrict__ bid,
                              float* __restrict__ com_sum, int* __restrict__ cnt_b) {
    int n = blockIdx.x * blockDim.x + threadIdx.x;
    if (n >= NA) return;
    int b = bid[n];
    atomicAdd(&cnt_b[b], 1);
    atomicAdd(&com_sum[b * 3 + 0], pos[n * 3 + 0]);
    atomicAdd(&com_sum[b * 3 + 1], pos[n * 3 + 1]);
    atomicAdd(&com_sum[b * 3 + 2], pos[n * 3 + 2]);
}

__global__ void k_count_edges(const int* __restrict__ row, int* __restrict__ cnt) {
    int e = blockIdx.x * blockDim.x + threadIdx.x;
    if (e < NE) atomicAdd(&cnt[row[e]], 1);
}

__global__ void k_com_finish(float* __restrict__ com, const float* __restrict__ com_sum,
                             const int* __restrict__ cnt_b) {
    int idx = blockIdx.x * blockDim.x + threadIdx.x;
    if (idx >= NG * 3) return;
    int g = idx / 3;
    float c = fmaxf((float)cnt_b[g], 1.0f);
    com[idx] = com_sum[idx] / c;
}

__global__ void k_edge_dist(const int* __restrict__ row, const int* __restrict__ col,
                            const float* __restrict__ pos, float* __restrict__ dist) {
    int e = blockIdx.x * blockDim.x + threadIdx.x;
    if (e >= NE) return;
    int r = row[e], c = col[e];
    float dx = pos[r * 3 + 0] - pos[c * 3 + 0];
    float dy = pos[r * 3 + 1] - pos[c * 3 + 1];
    float dz = pos[r * 3 + 2] - pos[c * 3 + 2];
    dist[e] = sqrtf(dx * dx + dy * dy + dz * dz);
}

__global__ void k_sph_scatter(const int* __restrict__ row, const int* __restrict__ col,
                              const float* __restrict__ pos, const float* __restrict__ msg,
                              float* __restrict__ sh_sum) {
    int e = blockIdx.x * blockDim.x + threadIdx.x;
    if (e >= NE) return;
    int r = row[e], c = col[e];
    float dx = pos[r * 3 + 0] - pos[c * 3 + 0];
    float dy = pos[r * 3 + 1] - pos[c * 3 + 1];
    float dz = pos[r * 3 + 2] - pos[c * 3 + 2];
    float s[9];
    sph9(dx, dy, dz, s);
    float w0 = msg[e * 3 + 0], w1 = msg[e * 3 + 1], w2 = msg[e * 3 + 2];
    float* dst = sh_sum + (size_t)r * 9;
    atomicAdd(&dst[0], s[0] * w0);
    atomicAdd(&dst[1], s[1] * w1);
    atomicAdd(&dst[2], s[2] * w1);
    atomicAdd(&dst[3], s[3] * w1);
    atomicAdd(&dst[4], s[4] * w2);
    atomicAdd(&dst[5], s[5] * w2);
    atomicAdd(&dst[6], s[6] * w2);
    atomicAdd(&dst[7], s[7] * w2);
    atomicAdd(&dst[8], s[8] * w2);
}

__global__ void k_sh_finish(const float* __restrict__ sh_sum, const int* __restrict__ cnt,
                            const float* __restrict__ pos, const float* __restrict__ com,
                            const int* __restrict__ bid, const float* __restrict__ msgC,
                            float* __restrict__ sh) {
    int n = blockIdx.x * blockDim.x + threadIdx.x;
    if (n >= NA) return;
    float cinv = 1.0f / fmaxf((float)cnt[n], 1.0f);
    int b = bid[n];
    float dx = pos[n * 3 + 0] - com[b * 3 + 0];
    float dy = pos[n * 3 + 1] - com[b * 3 + 1];
    float dz = pos[n * 3 + 2] - com[b * 3 + 2];
    float s[9];
    sph9(dx, dy, dz, s);
    float w2 = msgC[n * 3 + 2];
    // components 0..3 are zeroed by the reference (sh[:, :4] = 0)
    sh[n * 9 + 0] = 0.0f;
    sh[n * 9 + 1] = 0.0f;
    sh[n * 9 + 2] = 0.0f;
    sh[n * 9 + 3] = 0.0f;
#pragma unroll
    for (int j = 4; j < 9; j++)
        sh[n * 9 + j] = sh_sum[(size_t)n * 9 + j] * cinv + s[j] * w2;
}

__global__ void k_edge_pre(const int* __restrict__ row, const int* __restrict__ col,
                           const float* __restrict__ pos, const float* __restrict__ sh,
                           float* __restrict__ d2e, float* __restrict__ ipe) {
    int e = blockIdx.x * blockDim.x + threadIdx.x;
    if (e >= NE) return;
    int r = row[e], c = col[e];
    float dx = pos[r * 3 + 0] - pos[c * 3 + 0];
    float dy = pos[r * 3 + 1] - pos[c * 3 + 1];
    float dz = pos[r * 3 + 2] - pos[c * 3 + 2];
    d2e[e] = dx * dx + dy * dy + dz * dz;
    const float* sr = sh + (size_t)r * 9;
    const float* sc = sh + (size_t)c * 9;
    float ip0 = sr[0] * sc[0];
    float ip1 = sr[1] * sc[1] + sr[2] * sc[2] + sr[3] * sc[3];
    float ip2 = sr[4] * sc[4] + sr[5] * sc[5] + sr[6] * sc[6] + sr[7] * sc[7] + sr[8] * sc[8];
    ipe[e * 3 + 0] = ip0;
    ipe[e * 3 + 1] = ip1;
    ipe[e * 3 + 2] = ip2;
}

__global__ void k_scatter_m(const float* __restrict__ m, const int* __restrict__ row,
                            float* __restrict__ m_sum) {
    int idx = blockIdx.x * blockDim.x + threadIdx.x;
    if (idx >= NE * DF) return;
    int e = idx >> 7;
    int c = idx & 127;
    atomicAdd(&m_sum[(size_t)row[e] * DF + c], m[idx]);
}

__global__ void k_scatter_ps(const int* __restrict__ row, const int* __restrict__ col,
                             const float* __restrict__ pos, const float* __restrict__ sh,
                             const float* __restrict__ psc, const float* __restrict__ ssc,
                             float* __restrict__ p_sum, float* __restrict__ s_sum) {
    int e = blockIdx.x * blockDim.x + threadIdx.x;
    if (e >= NE) return;
    int r = row[e], c = col[e];
    float p = psc[e];
    float dx = pos[r * 3 + 0] - pos[c * 3 + 0];
    float dy = pos[r * 3 + 1] - pos[c * 3 + 1];
    float dz = pos[r * 3 + 2] - pos[c * 3 + 2];
    atomicAdd(&p_sum[r * 3 + 0], dx * p);
    atomicAdd(&p_sum[r * 3 + 1], dy * p);
    atomicAdd(&p_sum[r * 3 + 2], dz * p);
    float w0 = ssc[e * 3 + 0], w1 = ssc[e * 3 + 1], w2 = ssc[e * 3 + 2];
    const float* sr = sh + (size_t)r * 9;
    const float* sc = sh + (size_t)c * 9;
    float* dst = s_sum + (size_t)r * 9;
    atomicAdd(&dst[0], (sr[0] - sc[0]) * w0);
    atomicAdd(&dst[1], (sr[1] - sc[1]) * w1);
    atomicAdd(&dst[2], (sr[2] - sc[2]) * w1);
    atomicAdd(&dst[3], (sr[3] - sc[3]) * w1);
    atomicAdd(&dst[4], (sr[4] - sc[4]) * w2);
    atomicAdd(&dst[5], (sr[5] - sc[5]) * w2);
    atomicAdd(&dst[6], (sr[6] - sc[6]) * w2);
    atomicAdd(&dst[7], (sr[7] - sc[7]) * w2);
    atomicAdd(&dst[8], (sr[8] - sc[8]) * w2);
}

__global__ void k_update_nodes(float* __restrict__ sh, float* __restrict__ pos,
                               const float* __restrict__ s_sum, const float* __restrict__ p_sum,
                               const int* __restrict__ cnt) {
    int n = blockIdx.x * blockDim.x + threadIdx.x;
    if (n >= NA) return;
    float cinv = 1.0f / fmaxf((float)cnt[n], 1.0f);
#pragma unroll
    for (int j = 0; j < 9; j++) sh[n * 9 + j] += s_sum[(size_t)n * 9 + j] * cinv;
#pragma unroll
    for (int j = 0; j < 3; j++) pos[n * 3 + j] += p_sum[(size_t)n * 3 + j] * cinv;
}

__global__ void k_build_xn(const float* __restrict__ feat, const float* __restrict__ m_sum,
                           const int* __restrict__ cnt, float* __restrict__ Xn) {
    int idx = blockIdx.x * blockDim.x + threadIdx.x;
    if (idx >= NA * 256) return;
    int n = idx >> 8;
    int c = idx & 255;
    float v;
    if (c < 128) v = feat[(size_t)n * DF + c];
    else v = m_sum[(size_t)n * DF + (c - 128)] / fmaxf((float)cnt[n], 1.0f);
    Xn[idx] = v;
}

__global__ void k_pool(const float* __restrict__ feat, const float* __restrict__ pos,
                       const float* __restrict__ sh, const int* __restrict__ bid,
                       float* __restrict__ pooled) {
    int idx = blockIdx.x * blockDim.x + threadIdx.x;
    if (idx >= NA * 140) return;
    int n = idx / 140;
    int c = idx - n * 140;
    float v;
    if (c < 128)      v = feat[(size_t)n * DF + c];
    else if (c < 131) v = pos[n * 3 + (c - 128)];
    else              v = sh[n * 9 + (c - 131)];
    atomicAdd(&pooled[bid[n] * 140 + c], v);
}

__global__ void k_pred(const float* __restrict__ pooled, const float* __restrict__ Wp,
                       const float* __restrict__ bp, float* __restrict__ out) {
    int g = blockIdx.x;
    int lane = threadIdx.x;  // 64
    float s = 0.0f;
    for (int k = lane; k < 140; k += 64) s += pooled[g * 140 + k] * Wp[k];
#pragma unroll
    for (int off = 32; off > 0; off >>= 1) s += __shfl_down(s, off, 64);
    if (lane == 0) out[g] = s + bp[0];
}

// ---------------------------------------------------------------------------
extern "C" void kernel_launch(void* const* d_in, const int* in_sizes, int n_in,
                              void* d_out, int out_size, void* d_ws, size_t ws_size,
                              hipStream_t stream) {
    const int*   atoms  = (const int*)d_in[0];
    const int*   eidx   = (const int*)d_in[1];
    const int*   row    = eidx;
    const int*   col    = eidx + NE;
    const int*   bid    = (const int*)d_in[2];
    const float* pos_in = (const float*)d_in[3];
    const float* emb    = (const float*)d_in[4];
    const float* Wsi1   = (const float*)d_in[5];
    const float* bsi1   = (const float*)d_in[6];
    const float* Wsi2   = (const float*)d_in[7];
    const float* bsi2   = (const float*)d_in[8];
    const float* WsiC1  = (const float*)d_in[9];
    const float* bsiC1  = (const float*)d_in[10];
    const float* WsiC2  = (const float*)d_in[11];
    const float* bsiC2  = (const float*)d_in[12];
    const float* Wm1    = (const float*)d_in[13];
    const float* bm1    = (const float*)d_in[14];
    const float* Wm2    = (const float*)d_in[15];
    const float* bm2    = (const float*)d_in[16];
    const float* Wp1    = (const float*)d_in[17];
    const float* bp1    = (const float*)d_in[18];
    const float* Wp2    = (const float*)d_in[19];
    const float* bp2    = (const float*)d_in[20];
    const float* Wn1    = (const float*)d_in[21];
    const float* bn1    = (const float*)d_in[22];
    const float* Wn2    = (const float*)d_in[23];
    const float* bn2    = (const float*)d_in[24];
    const float* Ws1    = (const float*)d_in[25];
    const float* bs1    = (const float*)d_in[26];
    const float* Ws2    = (const float*)d_in[27];
    const float* bs2    = (const float*)d_in[28];
    const float* Wpred  = (const float*)d_in[29];
    const float* bpred  = (const float*)d_in[30];

    float* base = (float*)d_ws;
    size_t off = 0;
    auto alloc = [&](size_t nfl) { float* r = base + off; off += nfl; return r; };
    float* bufH    = alloc((size_t)NE * DF);
    float* bufM    = alloc((size_t)NE * DF);
    float* d2e     = alloc(NE);            // also dist in init phase
    float* ipe     = alloc((size_t)NE * 3);
    float* sc3     = alloc((size_t)NE * 3);  // msg / sscale
    float* psc     = alloc(NE);
    float* feat    = alloc((size_t)NA * DF);
    float* hn      = alloc((size_t)NA * DF);
    float* Xn      = alloc((size_t)NA * 256);
    float* posc    = alloc((size_t)NA * 3);
    float* sh      = alloc((size_t)NA * 9);
    float* m_sum   = alloc((size_t)NA * DF);
    float* p_sum   = alloc((size_t)NA * 3);
    float* s_sum   = alloc((size_t)NA * 9);
    float* sh_sum  = alloc((size_t)NA * 9);
    float* com_sum = alloc(NG * 3);
    float* com     = alloc(NG * 3);
    float* msgC    = alloc((size_t)NA * 3);
    float* pooled  = alloc(NG * 140);
    int* cnt_row   = (int*)alloc(NA);
    int* cnt_b     = (int*)alloc(NG);

    const dim3 B256(256);
    const int gE = NE / 128;                    // 1250 full tiles
    const int gN = (NA + 127) / 128;            // 79

    // ---------- setup ----------
    hipMemsetAsync(cnt_row, 0, NA * sizeof(int), stream);
    hipMemsetAsync(cnt_b, 0, NG * sizeof(int), stream);
    hipMemsetAsync(com_sum, 0, NG * 3 * sizeof(float), stream);
    hipMemsetAsync(sh_sum, 0, (size_t)NA * 9 * sizeof(float), stream);
    hipMemsetAsync(pooled, 0, NG * 140 * sizeof(float), stream);

    k_init_feat<<<(NA * DF + 255) / 256, B256, 0, stream>>>(atoms, emb, feat);
    k_copy_pos<<<(NA * 3 + 255) / 256, B256, 0, stream>>>(pos_in, posc);
    k_batch_stats<<<(NA + 255) / 256, B256, 0, stream>>>(pos_in, bid, com_sum, cnt_b);
    k_count_edges<<<(NE + 255) / 256, B256, 0, stream>>>(row, cnt_row);
    k_com_finish<<<(NG * 3 + 255) / 256, B256, 0, stream>>>(com, com_sum, cnt_b);

    // initial message MLP: [dist, feat[row], feat[col]] -> silu -> (E,3)
    k_edge_dist<<<(NE + 255) / 256, B256, 0, stream>>>(row, col, posc, d2e);
    gemm_fused<2, true><<<gE, B256, 0, stream>>>(nullptr, NE, 257, Wsi1, bsi1, bufH,
                                                 row, col, feat, d2e, nullptr);
    mlp_out_small<3><<<NE / 4, B256, 0, stream>>>(bufH, Wsi2, bsi2, sc3, NE);
    k_sph_scatter<<<(NE + 255) / 256, B256, 0, stream>>>(row, col, posc, sc3, sh_sum);

    // center term: MLP(feat) -> (N,3)
    gemm_fused<0, true><<<gN, B256, 0, stream>>>(feat, NA, 128, WsiC1, bsiC1, hn,
                                                 nullptr, nullptr, nullptr, nullptr, nullptr);
    mlp_out_small<3><<<NA / 4, B256, 0, stream>>>(hn, WsiC2, bsiC2, msgC, NA);
    k_sh_finish<<<(NA + 255) / 256, B256, 0, stream>>>(sh_sum, cnt_row, posc, com, bid, msgC, sh);

    // ---------- layers ----------
    for (int l = 0; l < NL; l++) {
        const float* wm1 = Wm1 + (size_t)l * 260 * 128;
        const float* cm1 = bm1 + l * 128;
        const float* wm2 = Wm2 + (size_t)l * 128 * 128;
        const float* cm2 = bm2 + l * 128;
        const float* wp1 = Wp1 + (size_t)l * 128 * 128;
        const float* cp1 = bp1 + l * 128;
        const float* wp2 = Wp2 + (size_t)l * 128;
        const float* cp2 = bp2 + l;
        const float* wn1 = Wn1 + (size_t)l * 256 * 128;
        const float* cn1 = bn1 + l * 128;
        const float* wn2 = Wn2 + (size_t)l * 128 * 128;
        const float* cn2 = bn2 + l * 128;
        const float* ws1 = Ws1 + (size_t)l * 128 * 128;
        const float* cs1 = bs1 + l * 128;
        const float* ws2 = Ws2 + (size_t)l * 128 * 3;
        const float* cs2 = bs2 + l * 3;

        hipMemsetAsync(m_sum, 0, (size_t)NA * DF * sizeof(float), stream);
        hipMemsetAsync(p_sum, 0, (size_t)NA * 3 * sizeof(float), stream);
        hipMemsetAsync(s_sum, 0, (size_t)NA * 9 * sizeof(float), stream);

        k_edge_pre<<<(NE + 255) / 256, B256, 0, stream>>>(row, col, posc, sh, d2e, ipe);
        // m = silu(silu(X @ wm1 + cm1) @ wm2 + cm2)
        gemm_fused<1, true><<<gE, B256, 0, stream>>>(nullptr, NE, 260, wm1, cm1, bufH,
                                                     row, col, feat, d2e, ipe);
        gemm_fused<0, true><<<gE, B256, 0, stream>>>(bufH, NE, 128, wm2, cm2, bufM,
                                                     nullptr, nullptr, nullptr, nullptr, nullptr);
        // p-scale = silu(m @ wp1 + cp1) @ wp2 + cp2
        gemm_fused<0, true><<<gE, B256, 0, stream>>>(bufM, NE, 128, wp1, cp1, bufH,
                                                     nullptr, nullptr, nullptr, nullptr, nullptr);
        mlp_out_small<1><<<NE / 4, B256, 0, stream>>>(bufH, wp2, cp2, psc, NE);
        // s-scale = silu(m @ ws1 + cs1) @ ws2 + cs2
        gemm_fused<0, true><<<gE, B256, 0, stream>>>(bufM, NE, 128, ws1, cs1, bufH,
                                                     nullptr, nullptr, nullptr, nullptr, nullptr);
        mlp_out_small<3><<<NE / 4, B256, 0, stream>>>(bufH, ws2, cs2, sc3, NE);

        k_scatter_m<<<(NE * DF) / 256, B256, 0, stream>>>(bufM, row, m_sum);
        k_scatter_ps<<<(NE + 255) / 256, B256, 0, stream>>>(row, col, posc, sh, psc, sc3,
                                                            p_sum, s_sum);
        k_update_nodes<<<(NA + 255) / 256, B256, 0, stream>>>(sh, posc, s_sum, p_sum, cnt_row);
        k_build_xn<<<(NA * 256 + 255) / 256, B256, 0, stream>>>(feat, m_sum, cnt_row, Xn);
        // feat = silu(Xn @ wn1 + cn1) @ wn2 + cn2
        gemm_fused<0, true><<<gN, B256, 0, stream>>>(Xn, NA, 256, wn1, cn1, hn,
                                                     nullptr, nullptr, nullptr, nullptr, nullptr);
        gemm_fused<0, false><<<gN, B256, 0, stream>>>(hn, NA, 128, wn2, cn2, feat,
                                                      nullptr, nullptr, nullptr, nullptr, nullptr);
    }

    // ---------- pooling + prediction ----------
    k_pool<<<(NA * 140 + 255) / 256, B256, 0, stream>>>(feat, posc, sh, bid, pooled);
    k_pred<<<NG, 64, 0, stream>>>(pooled, Wpred, bpred, (float*)d_out);
}

// Round 2
// 2381.932 us; speedup vs baseline: 3.0923x; 3.0923x over previous
//
#include <hip/hip_runtime.h>
#include <math.h>

#define NA 10000      // atoms
#define NE 160000     // edges
#define NG 100        // graphs
#define DF 128
#define NL 5
#define NAP 10112     // NA padded to 128-row tiles (79*128)

typedef __attribute__((ext_vector_type(8))) short bfx8;
typedef __attribute__((ext_vector_type(4))) float f32x4;

__device__ __forceinline__ float silu_f(float x) {
    return x / (1.0f + __expf(-x));
}

__device__ __forceinline__ unsigned short f2bf(float x) {
    unsigned u = __builtin_bit_cast(unsigned, x);
    u = (u + 0x7FFFu + ((u >> 16) & 1u)) >> 16;
    return (unsigned short)u;
}
__device__ __forceinline__ float bf2f(unsigned short h) {
    unsigned u = ((unsigned)h) << 16;
    return __builtin_bit_cast(float, u);
}
__device__ __forceinline__ unsigned packbf(float lo, float hi) {
    return (unsigned)f2bf(lo) | ((unsigned)f2bf(hi) << 16);
}

__device__ __forceinline__ void sph9(float dx, float dy, float dz, float* s) {
    float r = sqrtf(dx * dx + dy * dy + dz * dz);
    float inv = 1.0f / fmaxf(r, 1e-12f);
    float x = dx * inv, y = dy * inv, z = dz * inv;
    const float S3 = 1.7320508075688772f;
    s[0] = 1.0f;
    s[1] = x; s[2] = y; s[3] = z;
    s[4] = S3 * x * z;
    s[5] = S3 * x * y;
    s[6] = y * y - 0.5f * (x * x + z * z);
    s[7] = S3 * y * z;
    s[8] = 0.5f * S3 * (z * z - x * x);
}

// ---------------- weight prep: transpose + bf16, K padded to 32 -------------
// WT layout per matrix: [n=0..127][k=0..KPAD), row-major, zero-padded k>=K.
// si1 permuted: reference cols [dist, fr(128), fc(128)] -> [fr, fc, dist].
#define OFF_SI1   0
#define OFF_SIC1  36864
#define LBASE     53248
#define LSIZE     135168
#define LOFF_M1   0
#define LOFF_M2   36864
#define LOFF_P1   53248
#define LOFF_S1   69632
#define LOFF_N1   86016
#define LOFF_N2   118784
#define WT_TOTAL  729088   // 53248 + 5*135168

__global__ void k_prep_w(const float* __restrict__ Wsi1, const float* __restrict__ WsiC1,
                         const float* __restrict__ Wm1, const float* __restrict__ Wm2,
                         const float* __restrict__ Wp1, const float* __restrict__ Ws1,
                         const float* __restrict__ Wn1, const float* __restrict__ Wn2,
                         unsigned short* __restrict__ WT) {
    int flat = blockIdx.x * 256 + threadIdx.x;
    if (flat >= WT_TOTAL) return;
    float v = 0.0f;
    if (flat < OFF_SIC1) {                       // si1: K=257 -> KPAD=288, permuted
        int o = flat - OFF_SI1;
        int n = o / 288, k = o % 288;
        if (k < 256)       v = Wsi1[(k + 1) * 128 + n];
        else if (k == 256) v = Wsi1[n];
    } else if (flat < LBASE) {                   // siC1: K=128
        int o = flat - OFF_SIC1;
        int n = o / 128, k = o % 128;
        v = WsiC1[k * 128 + n];
    } else {
        int t = flat - LBASE;
        int lyr = t / LSIZE;
        int o = t % LSIZE;
        if (o < LOFF_M2) {                       // m1: K=260 -> 288
            int n = o / 288, k = o % 288;
            if (k < 260) v = Wm1[(size_t)lyr * 260 * 128 + k * 128 + n];
        } else if (o < LOFF_P1) {
            int o2 = o - LOFF_M2; int n = o2 / 128, k = o2 % 128;
            v = Wm2[(size_t)lyr * 16384 + k * 128 + n];
        } else if (o < LOFF_S1) {
            int o2 = o - LOFF_P1; int n = o2 / 128, k = o2 % 128;
            v = Wp1[(size_t)lyr * 16384 + k * 128 + n];
        } else if (o < LOFF_N1) {
            int o2 = o - LOFF_S1; int n = o2 / 128, k = o2 % 128;
            v = Ws1[(size_t)lyr * 16384 + k * 128 + n];
        } else if (o < LOFF_N2) {
            int o2 = o - LOFF_N1; int n = o2 / 256, k = o2 % 256;
            v = Wn1[(size_t)lyr * 32768 + k * 128 + n];
        } else {
            int o2 = o - LOFF_N2; int n = o2 / 128, k = o2 % 128;
            v = Wn2[(size_t)lyr * 16384 + k * 128 + n];
        }
    }
    WT[flat] = f2bf(v);
}

// ---------------- MFMA GEMM: C(M x 128) = act(A(M x KP) @ W + b) ------------
// MODE 0: A = bf16 buffer, row stride KP
// MODE 1: A = [featb[row](128) | featb[col](128) | tail(16, zero-padded)], KP=288
template <int KP, int MODE, bool ACT, bool F32OUT>
__global__ __launch_bounds__(256) void gemm_mfma(
    const unsigned short* __restrict__ Ab,
    const unsigned short* __restrict__ WT,
    const float* __restrict__ bias,
    unsigned short* __restrict__ Cb, float* __restrict__ Cf, int M,
    const int* __restrict__ rowI, const int* __restrict__ colI,
    const unsigned short* __restrict__ featb, const unsigned short* __restrict__ tailb)
{
    __shared__ unsigned short As[128 * 40];   // [m][k0..32), row stride 40 (80B, 16B-aligned, pad -> 2-way free)
    __shared__ unsigned short Bs[128 * 40];   // [n][k0..32)

    const int tid = threadIdx.x;
    const int m0 = blockIdx.x * 128;
    const int mlo = tid >> 2;        // 0..63
    const int part = tid & 3;        // 16B chunk within 64B row-slab

    int er0 = 0, ec0 = 0, er1 = 0, ec1 = 0;
    if (MODE == 1) {
        er0 = rowI[m0 + mlo];      ec0 = colI[m0 + mlo];
        er1 = rowI[m0 + mlo + 64]; ec1 = colI[m0 + mlo + 64];
    }

    const int w = tid >> 6;
    const int l = tid & 63;
    const int quad = l >> 4;
    const int lm = l & 15;
    const int wm = (w >> 1) * 64, wn = (w & 1) * 64;

    float bv[4];
#pragma unroll
    for (int j = 0; j < 4; j++) bv[j] = bias[wn + j * 16 + lm];

    f32x4 acc[4][4] = {};

    constexpr int NCH = KP / 32;
#pragma unroll 1
    for (int c = 0; c < NCH; c++) {
        const int k0 = c * 32;
#pragma unroll
        for (int i = 0; i < 2; i++) {
            const int m = mlo + i * 64;
            uint4 v;
            if (MODE == 0) {
                v = *(const uint4*)(Ab + (size_t)(m0 + m) * KP + k0 + part * 8);
            } else {
                if (k0 < 128) {
                    int e = i ? er1 : er0;
                    v = *(const uint4*)(featb + (size_t)e * 128 + k0 + part * 8);
                } else if (k0 < 256) {
                    int e = i ? ec1 : ec0;
                    v = *(const uint4*)(featb + (size_t)e * 128 + (k0 - 128) + part * 8);
                } else {
                    if (part == 0) v = *(const uint4*)(tailb + (size_t)(m0 + m) * 16);
                    else           v = make_uint4(0, 0, 0, 0);
                }
            }
            *(uint4*)&As[m * 40 + part * 8] = v;
            uint4 wv = *(const uint4*)(WT + (size_t)m * KP + k0 + part * 8);  // m doubles as n
            *(uint4*)&Bs[m * 40 + part * 8] = wv;
        }
        __syncthreads();
        bfx8 a[4], b[4];
#pragma unroll
        for (int i = 0; i < 4; i++) a[i] = *(const bfx8*)&As[(wm + i * 16 + lm) * 40 + quad * 8];
#pragma unroll
        for (int j = 0; j < 4; j++) b[j] = *(const bfx8*)&Bs[(wn + j * 16 + lm) * 40 + quad * 8];
#pragma unroll
        for (int i = 0; i < 4; i++)
#pragma unroll
            for (int j = 0; j < 4; j++)
                acc[i][j] = __builtin_amdgcn_mfma_f32_16x16x32_bf16(a[i], b[j], acc[i][j], 0, 0, 0);
        __syncthreads();
    }

#pragma unroll
    for (int i = 0; i < 4; i++) {
        const int rbase = wm + i * 16 + quad * 4;
#pragma unroll
        for (int r = 0; r < 4; r++) {
            const int e = m0 + rbase + r;
            if (e >= M) continue;
#pragma unroll
            for (int j = 0; j < 4; j++) {
                float v = acc[i][j][r] + bv[j];
                if (ACT) v = silu_f(v);
                const int colg = wn + j * 16 + lm;
                Cb[(size_t)e * 128 + colg] = f2bf(v);
                if (F32OUT) Cf[(size_t)e * 128 + colg] = v;
            }
        }
    }
}

// ---------------- small output layer: out(M x NO) = H(M x 128) @ W2 + b2 -----
template <int NO>
__global__ __launch_bounds__(256) void mlp_out_small(
    const unsigned short* __restrict__ H, const float* __restrict__ W2,
    const float* __restrict__ b2, float* __restrict__ out, int M)
{
    __shared__ float Ws[128 * NO];
    int tid = threadIdx.x;
    for (int i = tid; i < 128 * NO; i += 256) Ws[i] = W2[i];
    __syncthreads();
    int wave = tid >> 6;
    int lane = tid & 63;
    int m = blockIdx.x * 4 + wave;
    if (m >= M) return;
    float h0 = bf2f(H[(size_t)m * DF + lane]);
    float h1 = bf2f(H[(size_t)m * DF + 64 + lane]);
#pragma unroll
    for (int j = 0; j < NO; j++) {
        float s = h0 * Ws[lane * NO + j] + h1 * Ws[(64 + lane) * NO + j];
#pragma unroll
        for (int off = 32; off > 0; off >>= 1) s += __shfl_down(s, off, 64);
        if (lane == 0) out[(size_t)m * NO + j] = s + b2[j];
    }
}

// ---------------- misc small kernels ----------------------------------------
__global__ void k_init_feat(const int* __restrict__ atoms,
                            const float* __restrict__ emb,
                            float* __restrict__ feat, unsigned short* __restrict__ featb) {
    int idx = blockIdx.x * blockDim.x + threadIdx.x;
    if (idx >= NA * DF) return;
    float v = emb[atoms[idx >> 7] * DF + (idx & 127)];
    feat[idx] = v;
    featb[idx] = f2bf(v);
}

__global__ void k_copy_pos(const float* __restrict__ pos, float* __restrict__ posc) {
    int idx = blockIdx.x * blockDim.x + threadIdx.x;
    if (idx < NA * 3) posc[idx] = pos[idx];
}

__global__ void k_batch_stats(const float* __restrict__ pos, const int* __restrict__ bid,
                              float* __restrict__ com_sum, int* __restrict__ cnt_b) {
    int n = blockIdx.x * blockDim.x + threadIdx.x;
    if (n >= NA) return;
    int b = bid[n];
    atomicAdd(&cnt_b[b], 1);
    atomicAdd(&com_sum[b * 3 + 0], pos[n * 3 + 0]);
    atomicAdd(&com_sum[b * 3 + 1], pos[n * 3 + 1]);
    atomicAdd(&com_sum[b * 3 + 2], pos[n * 3 + 2]);
}

__global__ void k_count_edges(const int* __restrict__ row, int* __restrict__ cnt) {
    int e = blockIdx.x * blockDim.x + threadIdx.x;
    if (e < NE) atomicAdd(&cnt[row[e]], 1);
}

__global__ void k_com_finish(float* __restrict__ com, const float* __restrict__ com_sum,
                             const int* __restrict__ cnt_b) {
    int idx = blockIdx.x * blockDim.x + threadIdx.x;
    if (idx >= NG * 3) return;
    int g = idx / 3;
    float c = fmaxf((float)cnt_b[g], 1.0f);
    com[idx] = com_sum[idx] / c;
}

// initial-phase tail: [dist, 0 x15]
__global__ void k_tail_init(const int* __restrict__ row, const int* __restrict__ col,
                            const float* __restrict__ pos, unsigned short* __restrict__ tailb) {
    int e = blockIdx.x * blockDim.x + threadIdx.x;
    if (e >= NE) return;
    int r = row[e], c = col[e];
    float dx = pos[r * 3 + 0] - pos[c * 3 + 0];
    float dy = pos[r * 3 + 1] - pos[c * 3 + 1];
    float dz = pos[r * 3 + 2] - pos[c * 3 + 2];
    float dist = sqrtf(dx * dx + dy * dy + dz * dz);
    uint4 t0 = make_uint4(packbf(dist, 0.0f), 0, 0, 0);
    uint4 z = make_uint4(0, 0, 0, 0);
    *(uint4*)(tailb + (size_t)e * 16) = t0;
    *(uint4*)(tailb + (size_t)e * 16 + 8) = z;
}

__global__ void k_sph_scatter(const int* __restrict__ row, const int* __restrict__ col,
                              const float* __restrict__ pos, const float* __restrict__ msg,
                              float* __restrict__ sh_sum) {
    int e = blockIdx.x * blockDim.x + threadIdx.x;
    if (e >= NE) return;
    int r = row[e], c = col[e];
    float dx = pos[r * 3 + 0] - pos[c * 3 + 0];
    float dy = pos[r * 3 + 1] - pos[c * 3 + 1];
    float dz = pos[r * 3 + 2] - pos[c * 3 + 2];
    float s[9];
    sph9(dx, dy, dz, s);
    float w0 = msg[e * 3 + 0], w1 = msg[e * 3 + 1], w2 = msg[e * 3 + 2];
    float* dst = sh_sum + (size_t)r * 9;
    atomicAdd(&dst[0], s[0] * w0);
    atomicAdd(&dst[1], s[1] * w1);
    atomicAdd(&dst[2], s[2] * w1);
    atomicAdd(&dst[3], s[3] * w1);
    atomicAdd(&dst[4], s[4] * w2);
    atomicAdd(&dst[5], s[5] * w2);
    atomicAdd(&dst[6], s[6] * w2);
    atomicAdd(&dst[7], s[7] * w2);
    atomicAdd(&dst[8], s[8] * w2);
}

__global__ void k_sh_finish(const float* __restrict__ sh_sum, const int* __restrict__ cnt,
                            const float* __restrict__ pos, const float* __restrict__ com,
                            const int* __restrict__ bid, const float* __restrict__ msgC,
                            float* __restrict__ sh) {
    int n = blockIdx.x * blockDim.x + threadIdx.x;
    if (n >= NA) return;
    float cinv = 1.0f / fmaxf((float)cnt[n], 1.0f);
    int b = bid[n];
    float dx = pos[n * 3 + 0] - com[b * 3 + 0];
    float dy = pos[n * 3 + 1] - com[b * 3 + 1];
    float dz = pos[n * 3 + 2] - com[b * 3 + 2];
    float s[9];
    sph9(dx, dy, dz, s);
    float w2 = msgC[n * 3 + 2];
    sh[n * 9 + 0] = 0.0f;
    sh[n * 9 + 1] = 0.0f;
    sh[n * 9 + 2] = 0.0f;
    sh[n * 9 + 3] = 0.0f;
#pragma unroll
    for (int j = 4; j < 9; j++)
        sh[n * 9 + j] = sh_sum[(size_t)n * 9 + j] * cinv + s[j] * w2;
}

// per-layer tail: [d2, ip0, ip1, ip2, 0 x12]
__global__ void k_edge_pre(const int* __restrict__ row, const int* __restrict__ col,
                           const float* __restrict__ pos, const float* __restrict__ sh,
                           unsigned short* __restrict__ tailb) {
    int e = blockIdx.x * blockDim.x + threadIdx.x;
    if (e >= NE) return;
    int r = row[e], c = col[e];
    float dx = pos[r * 3 + 0] - pos[c * 3 + 0];
    float dy = pos[r * 3 + 1] - pos[c * 3 + 1];
    float dz = pos[r * 3 + 2] - pos[c * 3 + 2];
    float d2 = dx * dx + dy * dy + dz * dz;
    const float* sr = sh + (size_t)r * 9;
    const float* sc = sh + (size_t)c * 9;
    float ip0 = sr[0] * sc[0];
    float ip1 = sr[1] * sc[1] + sr[2] * sc[2] + sr[3] * sc[3];
    float ip2 = sr[4] * sc[4] + sr[5] * sc[5] + sr[6] * sc[6] + sr[7] * sc[7] + sr[8] * sc[8];
    uint4 t0 = make_uint4(packbf(d2, ip0), packbf(ip1, ip2), 0, 0);
    uint4 z = make_uint4(0, 0, 0, 0);
    *(uint4*)(tailb + (size_t)e * 16) = t0;
    *(uint4*)(tailb + (size_t)e * 16 + 8) = z;
}

__global__ void k_scatter_m(const unsigned short* __restrict__ m, const int* __restrict__ row,
                            float* __restrict__ m_sum) {
    int idx = blockIdx.x * blockDim.x + threadIdx.x;
    if (idx >= NE * DF) return;
    int e = idx >> 7;
    int c = idx & 127;
    atomicAdd(&m_sum[(size_t)row[e] * DF + c], bf2f(m[idx]));
}

__global__ void k_scatter_ps(const int* __restrict__ row, const int* __restrict__ col,
                             const float* __restrict__ pos, const float* __restrict__ sh,
                             const float* __restrict__ psc, const float* __restrict__ ssc,
                             float* __restrict__ p_sum, float* __restrict__ s_sum) {
    int e = blockIdx.x * blockDim.x + threadIdx.x;
    if (e >= NE) return;
    int r = row[e], c = col[e];
    float p = psc[e];
    float dx = pos[r * 3 + 0] - pos[c * 3 + 0];
    float dy = pos[r * 3 + 1] - pos[c * 3 + 1];
    float dz = pos[r * 3 + 2] - pos[c * 3 + 2];
    atomicAdd(&p_sum[r * 3 + 0], dx * p);
    atomicAdd(&p_sum[r * 3 + 1], dy * p);
    atomicAdd(&p_sum[r * 3 + 2], dz * p);
    float w0 = ssc[e * 3 + 0], w1 = ssc[e * 3 + 1], w2 = ssc[e * 3 + 2];
    const float* sr = sh + (size_t)r * 9;
    const float* sc = sh + (size_t)c * 9;
    float* dst = s_sum + (size_t)r * 9;
    atomicAdd(&dst[0], (sr[0] - sc[0]) * w0);
    atomicAdd(&dst[1], (sr[1] - sc[1]) * w1);
    atomicAdd(&dst[2], (sr[2] - sc[2]) * w1);
    atomicAdd(&dst[3], (sr[3] - sc[3]) * w1);
    atomicAdd(&dst[4], (sr[4] - sc[4]) * w2);
    atomicAdd(&dst[5], (sr[5] - sc[5]) * w2);
    atomicAdd(&dst[6], (sr[6] - sc[6]) * w2);
    atomicAdd(&dst[7], (sr[7] - sc[7]) * w2);
    atomicAdd(&dst[8], (sr[8] - sc[8]) * w2);
}

__global__ void k_update_nodes(float* __restrict__ sh, float* __restrict__ pos,
                               const float* __restrict__ s_sum, const float* __restrict__ p_sum,
                               const int* __restrict__ cnt) {
    int n = blockIdx.x * blockDim.x + threadIdx.x;
    if (n >= NA) return;
    float cinv = 1.0f / fmaxf((float)cnt[n], 1.0f);
#pragma unroll
    for (int j = 0; j < 9; j++) sh[n * 9 + j] += s_sum[(size_t)n * 9 + j] * cinv;
#pragma unroll
    for (int j = 0; j < 3; j++) pos[n * 3 + j] += p_sum[(size_t)n * 3 + j] * cinv;
}

__global__ void k_build_xn(const unsigned short* __restrict__ featb,
                           const float* __restrict__ m_sum,
                           const int* __restrict__ cnt, unsigned short* __restrict__ Xnb) {
    int idx = blockIdx.x * blockDim.x + threadIdx.x;
    if (idx >= NA * 256) return;
    int n = idx >> 8;
    int c = idx & 255;
    unsigned short v;
    if (c < 128) v = featb[(size_t)n * DF + c];
    else v = f2bf(m_sum[(size_t)n * DF + (c - 128)] / fmaxf((float)cnt[n], 1.0f));
    Xnb[idx] = v;
}

__global__ void k_pool(const float* __restrict__ feat, const float* __restrict__ pos,
                       const float* __restrict__ sh, const int* __restrict__ bid,
                       float* __restrict__ pooled) {
    int idx = blockIdx.x * blockDim.x + threadIdx.x;
    if (idx >= NA * 140) return;
    int n = idx / 140;
    int c = idx - n * 140;
    float v;
    if (c < 128)      v = feat[(size_t)n * DF + c];
    else if (c < 131) v = pos[n * 3 + (c - 128)];
    else              v = sh[n * 9 + (c - 131)];
    atomicAdd(&pooled[bid[n] * 140 + c], v);
}

__global__ void k_pred(const float* __restrict__ pooled, const float* __restrict__ Wp,
                       const float* __restrict__ bp, float* __restrict__ out) {
    int g = blockIdx.x;
    int lane = threadIdx.x;  // 64
    float s = 0.0f;
    for (int k = lane; k < 140; k += 64) s += pooled[g * 140 + k] * Wp[k];
#pragma unroll
    for (int off = 32; off > 0; off >>= 1) s += __shfl_down(s, off, 64);
    if (lane == 0) out[g] = s + bp[0];
}

// ---------------------------------------------------------------------------
extern "C" void kernel_launch(void* const* d_in, const int* in_sizes, int n_in,
                              void* d_out, int out_size, void* d_ws, size_t ws_size,
                              hipStream_t stream) {
    const int*   atoms  = (const int*)d_in[0];
    const int*   eidx   = (const int*)d_in[1];
    const int*   row    = eidx;
    const int*   col    = eidx + NE;
    const int*   bid    = (const int*)d_in[2];
    const float* pos_in = (const float*)d_in[3];
    const float* emb    = (const float*)d_in[4];
    const float* Wsi1   = (const float*)d_in[5];
    const float* bsi1   = (const float*)d_in[6];
    const float* Wsi2   = (const float*)d_in[7];
    const float* bsi2   = (const float*)d_in[8];
    const float* WsiC1  = (const float*)d_in[9];
    const float* bsiC1  = (const float*)d_in[10];
    const float* WsiC2  = (const float*)d_in[11];
    const float* bsiC2  = (const float*)d_in[12];
    const float* Wm1    = (const float*)d_in[13];
    const float* bm1    = (const float*)d_in[14];
    const float* Wm2    = (const float*)d_in[15];
    const float* bm2    = (const float*)d_in[16];
    const float* Wp1    = (const float*)d_in[17];
    const float* bp1    = (const float*)d_in[18];
    const float* Wp2    = (const float*)d_in[19];
    const float* bp2    = (const float*)d_in[20];
    const float* Wn1    = (const float*)d_in[21];
    const float* bn1    = (const float*)d_in[22];
    const float* Wn2    = (const float*)d_in[23];
    const float* bn2    = (const float*)d_in[24];
    const float* Ws1    = (const float*)d_in[25];
    const float* bs1    = (const float*)d_in[26];
    const float* Ws2    = (const float*)d_in[27];
    const float* bs2    = (const float*)d_in[28];
    const float* Wpred  = (const float*)d_in[29];
    const float* bpred  = (const float*)d_in[30];

    float* base = (float*)d_ws;
    size_t off = 0;
    auto alloc = [&](size_t nfl) { float* r = base + off; off += nfl; return r; };
    // bf16 buffers (sized in floats = nushort/2, all multiples of 4)
    unsigned short* bufHb = (unsigned short*)alloc((size_t)NE * DF / 2);
    unsigned short* bufMb = (unsigned short*)alloc((size_t)NE * DF / 2);
    unsigned short* featb = (unsigned short*)alloc((size_t)NAP * DF / 2);
    unsigned short* hnb   = (unsigned short*)alloc((size_t)NAP * DF / 2);
    unsigned short* Xnb   = (unsigned short*)alloc((size_t)NAP * 256 / 2);
    unsigned short* tailb = (unsigned short*)alloc((size_t)NE * 16 / 2);
    unsigned short* WT    = (unsigned short*)alloc(WT_TOTAL / 2);
    // fp32 buffers
    float* feat    = alloc((size_t)NAP * DF);
    float* sc3     = alloc((size_t)NE * 3);
    float* psc     = alloc(NE);
    float* posc    = alloc((size_t)NA * 3 + 4);
    float* sh      = alloc((size_t)NA * 9 + 4);
    float* m_sum   = alloc((size_t)NA * DF);
    float* p_sum   = alloc((size_t)NA * 3 + 4);
    float* s_sum   = alloc((size_t)NA * 9 + 4);
    float* sh_sum  = alloc((size_t)NA * 9 + 4);
    float* com_sum = alloc(NG * 3 + 4);
    float* com     = alloc(NG * 3 + 4);
    float* msgC    = alloc((size_t)NA * 3 + 4);
    float* pooled  = alloc(NG * 140);
    int* cnt_row   = (int*)alloc(NA);
    int* cnt_b     = (int*)alloc(NG);

    const dim3 B256(256);
    const int gE = NE / 128;                    // 1250
    const int gN = (NAP) / 128;                 // 79

    // ---------- setup ----------
    hipMemsetAsync(cnt_row, 0, NA * sizeof(int), stream);
    hipMemsetAsync(cnt_b, 0, NG * sizeof(int), stream);
    hipMemsetAsync(com_sum, 0, NG * 3 * sizeof(float), stream);
    hipMemsetAsync(sh_sum, 0, (size_t)NA * 9 * sizeof(float), stream);
    hipMemsetAsync(pooled, 0, NG * 140 * sizeof(float), stream);

    k_prep_w<<<(WT_TOTAL + 255) / 256, B256, 0, stream>>>(Wsi1, WsiC1, Wm1, Wm2, Wp1, Ws1, Wn1, Wn2, WT);
    k_init_feat<<<(NA * DF + 255) / 256, B256, 0, stream>>>(atoms, emb, feat, featb);
    k_copy_pos<<<(NA * 3 + 255) / 256, B256, 0, stream>>>(pos_in, posc);
    k_batch_stats<<<(NA + 255) / 256, B256, 0, stream>>>(pos_in, bid, com_sum, cnt_b);
    k_count_edges<<<(NE + 255) / 256, B256, 0, stream>>>(row, cnt_row);
    k_com_finish<<<(NG * 3 + 255) / 256, B256, 0, stream>>>(com, com_sum, cnt_b);

    // initial message MLP: [fr|fc|dist] @ WT_si1 -> silu -> small out (E,3)
    k_tail_init<<<(NE + 255) / 256, B256, 0, stream>>>(row, col, posc, tailb);
    gemm_mfma<288, 1, true, false><<<gE, B256, 0, stream>>>(
        nullptr, WT + OFF_SI1, bsi1, bufHb, nullptr, NE, row, col, featb, tailb);
    mlp_out_small<3><<<NE / 4, B256, 0, stream>>>(bufHb, Wsi2, bsi2, sc3, NE);
    k_sph_scatter<<<(NE + 255) / 256, B256, 0, stream>>>(row, col, posc, sc3, sh_sum);

    // center term
    gemm_mfma<128, 0, true, false><<<gN, B256, 0, stream>>>(
        featb, WT + OFF_SIC1, bsiC1, hnb, nullptr, NA, nullptr, nullptr, nullptr, nullptr);
    mlp_out_small<3><<<(NA + 3) / 4, B256, 0, stream>>>(hnb, WsiC2, bsiC2, msgC, NA);
    k_sh_finish<<<(NA + 255) / 256, B256, 0, stream>>>(sh_sum, cnt_row, posc, com, bid, msgC, sh);

    // ---------- layers ----------
    for (int l = 0; l < NL; l++) {
        const unsigned short* wtL = WT + LBASE + (size_t)l * LSIZE;
        const float* cm1 = bm1 + l * 128;
        const float* cm2 = bm2 + l * 128;
        const float* cp1 = bp1 + l * 128;
        const float* wp2 = Wp2 + (size_t)l * 128;
        const float* cp2 = bp2 + l;
        const float* cn1 = bn1 + l * 128;
        const float* cn2 = bn2 + l * 128;
        const float* cs1 = bs1 + l * 128;
        const float* ws2 = Ws2 + (size_t)l * 128 * 3;
        const float* cs2 = bs2 + l * 3;

        hipMemsetAsync(m_sum, 0, (size_t)NA * DF * sizeof(float), stream);
        hipMemsetAsync(p_sum, 0, (size_t)NA * 3 * sizeof(float), stream);
        hipMemsetAsync(s_sum, 0, (size_t)NA * 9 * sizeof(float), stream);

        k_edge_pre<<<(NE + 255) / 256, B256, 0, stream>>>(row, col, posc, sh, tailb);
        gemm_mfma<288, 1, true, false><<<gE, B256, 0, stream>>>(
            nullptr, wtL + LOFF_M1, cm1, bufHb, nullptr, NE, row, col, featb, tailb);
        gemm_mfma<128, 0, true, false><<<gE, B256, 0, stream>>>(
            bufHb, wtL + LOFF_M2, cm2, bufMb, nullptr, NE, nullptr, nullptr, nullptr, nullptr);
        gemm_mfma<128, 0, true, false><<<gE, B256, 0, stream>>>(
            bufMb, wtL + LOFF_P1, cp1, bufHb, nullptr, NE, nullptr, nullptr, nullptr, nullptr);
        mlp_out_small<1><<<NE / 4, B256, 0, stream>>>(bufHb, wp2, cp2, psc, NE);
        gemm_mfma<128, 0, true, false><<<gE, B256, 0, stream>>>(
            bufMb, wtL + LOFF_S1, cs1, bufHb, nullptr, NE, nullptr, nullptr, nullptr, nullptr);
        mlp_out_small<3><<<NE / 4, B256, 0, stream>>>(bufHb, ws2, cs2, sc3, NE);

        k_scatter_m<<<(NE * DF) / 256, B256, 0, stream>>>(bufMb, row, m_sum);
        k_scatter_ps<<<(NE + 255) / 256, B256, 0, stream>>>(row, col, posc, sh, psc, sc3,
                                                            p_sum, s_sum);
        k_update_nodes<<<(NA + 255) / 256, B256, 0, stream>>>(sh, posc, s_sum, p_sum, cnt_row);
        k_build_xn<<<(NA * 256 + 255) / 256, B256, 0, stream>>>(featb, m_sum, cnt_row, Xnb);
        gemm_mfma<256, 0, true, false><<<gN, B256, 0, stream>>>(
            Xnb, wtL + LOFF_N1, cn1, hnb, nullptr, NA, nullptr, nullptr, nullptr, nullptr);
        gemm_mfma<128, 0, false, true><<<gN, B256, 0, stream>>>(
            hnb, wtL + LOFF_N2, cn2, featb, feat, NA, nullptr, nullptr, nullptr, nullptr);
    }

    // ---------- pooling + prediction ----------
    k_pool<<<(NA * 140 + 255) / 256, B256, 0, stream>>>(feat, posc, sh, bid, pooled);
    k_pred<<<NG, 64, 0, stream>>>(pooled, Wpred, bpred, (float*)d_out);
}

// Round 3
// 1087.609 us; speedup vs baseline: 6.7724x; 2.1901x over previous
//
#include <hip/hip_runtime.h>
#include <math.h>

#define NA 10000      // atoms
#define NE 160000     // edges
#define NG 100        // graphs
#define DF 128
#define NL 5
#define NAP 10112     // NA padded to 128-row tiles (79*128)
#define NSB 40        // scan blocks = ceil(NA/256)

typedef __attribute__((ext_vector_type(8))) short bfx8;
typedef __attribute__((ext_vector_type(4))) float f32x4;

__device__ __forceinline__ float silu_f(float x) {
    return x / (1.0f + __expf(-x));
}

__device__ __forceinline__ unsigned short f2bf(float x) {
    unsigned u = __builtin_bit_cast(unsigned, x);
    u = (u + 0x7FFFu + ((u >> 16) & 1u)) >> 16;
    return (unsigned short)u;
}
__device__ __forceinline__ float bf2f(unsigned short h) {
    unsigned u = ((unsigned)h) << 16;
    return __builtin_bit_cast(float, u);
}
__device__ __forceinline__ unsigned packbf(float lo, float hi) {
    return (unsigned)f2bf(lo) | ((unsigned)f2bf(hi) << 16);
}

__device__ __forceinline__ void sph9(float dx, float dy, float dz, float* s) {
    float r = sqrtf(dx * dx + dy * dy + dz * dz);
    float inv = 1.0f / fmaxf(r, 1e-12f);
    float x = dx * inv, y = dy * inv, z = dz * inv;
    const float S3 = 1.7320508075688772f;
    s[0] = 1.0f;
    s[1] = x; s[2] = y; s[3] = z;
    s[4] = S3 * x * z;
    s[5] = S3 * x * y;
    s[6] = y * y - 0.5f * (x * x + z * z);
    s[7] = S3 * y * z;
    s[8] = 0.5f * S3 * (z * z - x * x);
}

// ---------------- weight prep: transpose + bf16, K padded to 32 -------------
#define OFF_SI1   0
#define OFF_SIC1  36864
#define LBASE     53248
#define LSIZE     135168
#define LOFF_M1   0
#define LOFF_M2   36864
#define LOFF_P1   53248
#define LOFF_S1   69632
#define LOFF_N1   86016
#define LOFF_N2   118784
#define WT_TOTAL  729088   // 53248 + 5*135168

__global__ void k_prep_w(const float* __restrict__ Wsi1, const float* __restrict__ WsiC1,
                         const float* __restrict__ Wm1, const float* __restrict__ Wm2,
                         const float* __restrict__ Wp1, const float* __restrict__ Ws1,
                         const float* __restrict__ Wn1, const float* __restrict__ Wn2,
                         unsigned short* __restrict__ WT) {
    int flat = blockIdx.x * 256 + threadIdx.x;
    if (flat >= WT_TOTAL) return;
    float v = 0.0f;
    if (flat < OFF_SIC1) {                       // si1: K=257 -> KPAD=288, permuted [fr|fc|dist]
        int o = flat - OFF_SI1;
        int n = o / 288, k = o % 288;
        if (k < 256)       v = Wsi1[(k + 1) * 128 + n];
        else if (k == 256) v = Wsi1[n];
    } else if (flat < LBASE) {                   // siC1: K=128
        int o = flat - OFF_SIC1;
        int n = o / 128, k = o % 128;
        v = WsiC1[k * 128 + n];
    } else {
        int t = flat - LBASE;
        int lyr = t / LSIZE;
        int o = t % LSIZE;
        if (o < LOFF_M2) {                       // m1: K=260 -> 288
            int n = o / 288, k = o % 288;
            if (k < 260) v = Wm1[(size_t)lyr * 260 * 128 + k * 128 + n];
        } else if (o < LOFF_P1) {
            int o2 = o - LOFF_M2; int n = o2 / 128, k = o2 % 128;
            v = Wm2[(size_t)lyr * 16384 + k * 128 + n];
        } else if (o < LOFF_S1) {
            int o2 = o - LOFF_P1; int n = o2 / 128, k = o2 % 128;
            v = Wp1[(size_t)lyr * 16384 + k * 128 + n];
        } else if (o < LOFF_N1) {
            int o2 = o - LOFF_S1; int n = o2 / 128, k = o2 % 128;
            v = Ws1[(size_t)lyr * 16384 + k * 128 + n];
        } else if (o < LOFF_N2) {
            int o2 = o - LOFF_N1; int n = o2 / 256, k = o2 % 256;
            v = Wn1[(size_t)lyr * 32768 + k * 128 + n];
        } else {
            int o2 = o - LOFF_N2; int n = o2 / 128, k = o2 % 128;
            v = Wn2[(size_t)lyr * 16384 + k * 128 + n];
        }
    }
    WT[flat] = f2bf(v);
}

// ---------------- MFMA GEMM: act(A(M x KP) @ W + b), optional fused W2 ------
// MODE 0: A = bf16 buffer, row stride KP
// MODE 1: A = [featb[row] | featb[col] | tail(32, zero-padded)], KP=288
// NOUT=0: write C (bf16 Cb, optional fp32 Cf). NOUT>0: out = actC @ W2 + b2 only.
template <int KP, int MODE, bool ACT, int NOUT, bool F32OUT>
__global__ __launch_bounds__(256) void gemm_mfma(
    const unsigned short* __restrict__ Ab,
    const unsigned short* __restrict__ WT,
    const float* __restrict__ bias,
    unsigned short* __restrict__ Cb, float* __restrict__ Cf, int M,
    const int* __restrict__ rowI, const int* __restrict__ colI,
    const unsigned short* __restrict__ featb, const unsigned short* __restrict__ tailb,
    const float* __restrict__ W2, const float* __restrict__ b2,
    float* __restrict__ outS)
{
    constexpr int NO = (NOUT > 0) ? NOUT : 1;
    __shared__ unsigned short As[128 * 40];   // [m][k], stride 40 -> 2-way bank alias (free)
    __shared__ unsigned short Bs[128 * 40];   // [n][k]
    __shared__ float W2s[128 * NO];
    __shared__ float sacc[128 * NO];

    const int tid = threadIdx.x;
    const int m0 = blockIdx.x * 128;
    const int mlo = tid >> 2;
    const int part = tid & 3;

    if (NOUT > 0) {
        for (int t = tid; t < 128 * NO; t += 256) {
            W2s[t] = W2[t];
            sacc[t] = 0.0f;
        }
    }

    int er0 = 0, ec0 = 0, er1 = 0, ec1 = 0;
    if (MODE == 1) {
        er0 = rowI[m0 + mlo];      ec0 = colI[m0 + mlo];
        er1 = rowI[m0 + mlo + 64]; ec1 = colI[m0 + mlo + 64];
    }

    const int w = tid >> 6;
    const int l = tid & 63;
    const int quad = l >> 4;
    const int lm = l & 15;
    const int wm = (w >> 1) * 64, wn = (w & 1) * 64;

    float bv[4];
#pragma unroll
    for (int j = 0; j < 4; j++) bv[j] = bias[wn + j * 16 + lm];

    f32x4 acc[4][4] = {};

    constexpr int NCH = KP / 32;
#pragma unroll 1
    for (int c = 0; c < NCH; c++) {
        const int k0 = c * 32;
#pragma unroll
        for (int i = 0; i < 2; i++) {
            const int m = mlo + i * 64;
            uint4 v;
            if (MODE == 0) {
                v = *(const uint4*)(Ab + (size_t)(m0 + m) * KP + k0 + part * 8);
            } else {
                if (k0 < 128) {
                    int e = i ? er1 : er0;
                    v = *(const uint4*)(featb + (size_t)e * 128 + k0 + part * 8);
                } else if (k0 < 256) {
                    int e = i ? ec1 : ec0;
                    v = *(const uint4*)(featb + (size_t)e * 128 + (k0 - 128) + part * 8);
                } else {
                    if (part == 0) v = *(const uint4*)(tailb + (size_t)(m0 + m) * 16);
                    else           v = make_uint4(0, 0, 0, 0);
                }
            }
            *(uint4*)&As[m * 40 + part * 8] = v;
            uint4 wv = *(const uint4*)(WT + (size_t)m * KP + k0 + part * 8);
            *(uint4*)&Bs[m * 40 + part * 8] = wv;
        }
        __syncthreads();
        bfx8 a[4], b[4];
#pragma unroll
        for (int i = 0; i < 4; i++) a[i] = *(const bfx8*)&As[(wm + i * 16 + lm) * 40 + quad * 8];
#pragma unroll
        for (int j = 0; j < 4; j++) b[j] = *(const bfx8*)&Bs[(wn + j * 16 + lm) * 40 + quad * 8];
#pragma unroll
        for (int i = 0; i < 4; i++)
#pragma unroll
            for (int j = 0; j < 4; j++)
                acc[i][j] = __builtin_amdgcn_mfma_f32_16x16x32_bf16(a[i], b[j], acc[i][j], 0, 0, 0);
        __syncthreads();
    }

    if (NOUT > 0) {
#pragma unroll
        for (int i = 0; i < 4; i++) {
#pragma unroll
            for (int r = 0; r < 4; r++) {
                const int rowL = wm + i * 16 + quad * 4 + r;
                float ps[NO];
#pragma unroll
                for (int o = 0; o < NO; o++) ps[o] = 0.0f;
#pragma unroll
                for (int j = 0; j < 4; j++) {
                    float v = acc[i][j][r] + bv[j];
                    if (ACT) v = silu_f(v);
                    const int colg = wn + j * 16 + lm;
#pragma unroll
                    for (int o = 0; o < NO; o++) ps[o] += v * W2s[colg * NO + o];
                }
#pragma unroll
                for (int off = 1; off < 16; off <<= 1)
#pragma unroll
                    for (int o = 0; o < NO; o++) ps[o] += __shfl_xor(ps[o], off, 64);
                if (lm == 0)
#pragma unroll
                    for (int o = 0; o < NO; o++) atomicAdd(&sacc[rowL * NO + o], ps[o]);
            }
        }
        __syncthreads();
        for (int t = tid; t < 128 * NO; t += 256) {
            int rowL = t / NO, o = t - rowL * NO;
            int e = m0 + rowL;
            if (e < M) outS[(size_t)e * NO + o] = sacc[t] + b2[o];
        }
    } else {
#pragma unroll
        for (int i = 0; i < 4; i++) {
            const int rbase = wm + i * 16 + quad * 4;
#pragma unroll
            for (int r = 0; r < 4; r++) {
                const int e = m0 + rbase + r;
                if (e >= M) continue;
#pragma unroll
                for (int j = 0; j < 4; j++) {
                    float v = acc[i][j][r] + bv[j];
                    if (ACT) v = silu_f(v);
                    const int colg = wn + j * 16 + lm;
                    Cb[(size_t)e * 128 + colg] = f2bf(v);
                    if (F32OUT) Cf[(size_t)e * 128 + colg] = v;
                }
            }
        }
    }
}

// ---------------- sort / scan -----------------------------------------------
__global__ void k_count_edges(const int* __restrict__ row, int* __restrict__ cnt) {
    int e = blockIdx.x * blockDim.x + threadIdx.x;
    if (e < NE) atomicAdd(&cnt[row[e]], 1);
}

__global__ void k_scan_block(const int* __restrict__ cnt, int* __restrict__ ptr,
                             int* __restrict__ btot) {
    __shared__ int s[256];
    int tid = threadIdx.x;
    int i = blockIdx.x * 256 + tid;
    int v = (i < NA) ? cnt[i] : 0;
    s[tid] = v;
    __syncthreads();
    for (int off = 1; off < 256; off <<= 1) {
        int t = (tid >= off) ? s[tid - off] : 0;
        __syncthreads();
        s[tid] += t;
        __syncthreads();
    }
    if (i < NA) ptr[i] = s[tid] - v;   // block-local exclusive
    if (tid == 255) btot[blockIdx.x] = s[255];
}

__global__ void k_scan_tot(int* __restrict__ btot) {
    int lane = threadIdx.x;
    int v = (lane < NSB) ? btot[lane] : 0;
    int orig = v;
    for (int off = 1; off < 64; off <<= 1) {
        int t = __shfl_up(v, off, 64);
        if (lane >= off) v += t;
    }
    if (lane < NSB) btot[lane] = v - orig;  // exclusive
}

__global__ void k_scan_add(int* __restrict__ ptr, const int* __restrict__ btot) {
    int i = blockIdx.x * 256 + threadIdx.x;
    if (i < NA) ptr[i] += btot[i >> 8];
    if (i == 0) ptr[NA] = NE;
}

__global__ void k_copy_cursor(const int* __restrict__ ptr, int* __restrict__ cursor) {
    int i = blockIdx.x * 256 + threadIdx.x;
    if (i < NA) cursor[i] = ptr[i];
}

__global__ void k_sort(const int* __restrict__ row, const int* __restrict__ col,
                       int* __restrict__ cursor,
                       int* __restrict__ row_s, int* __restrict__ col_s) {
    int e = blockIdx.x * blockDim.x + threadIdx.x;
    if (e >= NE) return;
    int r = row[e];
    int p = atomicAdd(&cursor[r], 1);
    row_s[p] = r;
    col_s[p] = col[e];
}

__global__ void k_gptr(const int* __restrict__ bid, int* __restrict__ gptr) {
    int n = blockIdx.x * blockDim.x + threadIdx.x;
    if (n >= NA) return;
    int b = bid[n];
    int bp = (n == 0) ? -1 : bid[n - 1];
    for (int g = bp + 1; g <= b; g++) gptr[g] = n;
    if (n == NA - 1)
        for (int g = b + 1; g <= NG; g++) gptr[g] = NA;
}

// ---------------- misc small kernels ----------------------------------------
__global__ void k_init_feat(const int* __restrict__ atoms,
                            const float* __restrict__ emb,
                            float* __restrict__ feat, unsigned short* __restrict__ featb) {
    int idx = blockIdx.x * blockDim.x + threadIdx.x;
    if (idx >= NA * DF) return;
    float v = emb[atoms[idx >> 7] * DF + (idx & 127)];
    feat[idx] = v;
    featb[idx] = f2bf(v);
}

__global__ void k_copy_pos(const float* __restrict__ pos, float* __restrict__ posc) {
    int idx = blockIdx.x * blockDim.x + threadIdx.x;
    if (idx < NA * 3) posc[idx] = pos[idx];
}

__global__ void k_com_g(const float* __restrict__ pos, const int* __restrict__ gptr,
                        float* __restrict__ com) {
    int g = blockIdx.x;
    int lane = threadIdx.x;  // 64
    int s0 = gptr[g], s1 = gptr[g + 1];
    float sx = 0.0f, sy = 0.0f, sz = 0.0f;
    for (int n = s0 + lane; n < s1; n += 64) {
        sx += pos[n * 3 + 0];
        sy += pos[n * 3 + 1];
        sz += pos[n * 3 + 2];
    }
#pragma unroll
    for (int off = 32; off > 0; off >>= 1) {
        sx += __shfl_down(sx, off, 64);
        sy += __shfl_down(sy, off, 64);
        sz += __shfl_down(sz, off, 64);
    }
    if (lane == 0) {
        float cinv = 1.0f / fmaxf((float)(s1 - s0), 1.0f);
        com[g * 3 + 0] = sx * cinv;
        com[g * 3 + 1] = sy * cinv;
        com[g * 3 + 2] = sz * cinv;
    }
}

// initial-phase tail: [dist, 0...]
__global__ void k_tail_init(const int* __restrict__ row, const int* __restrict__ col,
                            const float* __restrict__ pos, unsigned short* __restrict__ tailb) {
    int e = blockIdx.x * blockDim.x + threadIdx.x;
    if (e >= NE) return;
    int r = row[e], c = col[e];
    float dx = pos[r * 3 + 0] - pos[c * 3 + 0];
    float dy = pos[r * 3 + 1] - pos[c * 3 + 1];
    float dz = pos[r * 3 + 2] - pos[c * 3 + 2];
    float dist = sqrtf(dx * dx + dy * dy + dz * dz);
    uint4 t0 = make_uint4(packbf(dist, 0.0f), 0, 0, 0);
    uint4 z = make_uint4(0, 0, 0, 0);
    *(uint4*)(tailb + (size_t)e * 16) = t0;
    *(uint4*)(tailb + (size_t)e * 16 + 8) = z;
}

// gather version of sph scatter: one wave per node, edges contiguous
__global__ void k_gather_sph(const int* __restrict__ ptr, const int* __restrict__ col_s,
                             const float* __restrict__ pos, const float* __restrict__ msg,
                             float* __restrict__ sh_mean) {
    int n = blockIdx.x;
    int lane = threadIdx.x;  // 64
    int s0 = ptr[n], s1 = ptr[n + 1];
    float px = pos[n * 3 + 0], py = pos[n * 3 + 1], pz = pos[n * 3 + 2];
    float a[9];
#pragma unroll
    for (int j = 0; j < 9; j++) a[j] = 0.0f;
    for (int e = s0 + lane; e < s1; e += 64) {
        int c = col_s[e];
        float dx = px - pos[c * 3 + 0];
        float dy = py - pos[c * 3 + 1];
        float dz = pz - pos[c * 3 + 2];
        float s[9];
        sph9(dx, dy, dz, s);
        float w0 = msg[e * 3 + 0], w1 = msg[e * 3 + 1], w2 = msg[e * 3 + 2];
        a[0] += s[0] * w0;
        a[1] += s[1] * w1; a[2] += s[2] * w1; a[3] += s[3] * w1;
        a[4] += s[4] * w2; a[5] += s[5] * w2; a[6] += s[6] * w2;
        a[7] += s[7] * w2; a[8] += s[8] * w2;
    }
#pragma unroll
    for (int off = 32; off > 0; off >>= 1)
#pragma unroll
        for (int j = 0; j < 9; j++) a[j] += __shfl_down(a[j], off, 64);
    if (lane == 0) {
        float cinv = 1.0f / fmaxf((float)(s1 - s0), 1.0f);
#pragma unroll
        for (int j = 0; j < 9; j++) sh_mean[(size_t)n * 9 + j] = a[j] * cinv;
    }
}

__global__ void k_sh_finish(const float* __restrict__ sh_mean,
                            const float* __restrict__ pos, const float* __restrict__ com,
                            const int* __restrict__ bid, const float* __restrict__ msgC,
                            float* __restrict__ sh) {
    int n = blockIdx.x * blockDim.x + threadIdx.x;
    if (n >= NA) return;
    int b = bid[n];
    float dx = pos[n * 3 + 0] - com[b * 3 + 0];
    float dy = pos[n * 3 + 1] - com[b * 3 + 1];
    float dz = pos[n * 3 + 2] - com[b * 3 + 2];
    float s[9];
    sph9(dx, dy, dz, s);
    float w2 = msgC[n * 3 + 2];
    sh[n * 9 + 0] = 0.0f;
    sh[n * 9 + 1] = 0.0f;
    sh[n * 9 + 2] = 0.0f;
    sh[n * 9 + 3] = 0.0f;
#pragma unroll
    for (int j = 4; j < 9; j++)
        sh[n * 9 + j] = sh_mean[(size_t)n * 9 + j] + s[j] * w2;
}

// per-layer tail: [d2, ip0, ip1, ip2, 0...]
__global__ void k_edge_pre(const int* __restrict__ row, const int* __restrict__ col,
                           const float* __restrict__ pos, const float* __restrict__ sh,
                           unsigned short* __restrict__ tailb) {
    int e = blockIdx.x * blockDim.x + threadIdx.x;
    if (e >= NE) return;
    int r = row[e], c = col[e];
    float dx = pos[r * 3 + 0] - pos[c * 3 + 0];
    float dy = pos[r * 3 + 1] - pos[c * 3 + 1];
    float dz = pos[r * 3 + 2] - pos[c * 3 + 2];
    float d2 = dx * dx + dy * dy + dz * dz;
    const float* sr = sh + (size_t)r * 9;
    const float* sc = sh + (size_t)c * 9;
    float ip0 = sr[0] * sc[0];
    float ip1 = sr[1] * sc[1] + sr[2] * sc[2] + sr[3] * sc[3];
    float ip2 = sr[4] * sc[4] + sr[5] * sc[5] + sr[6] * sc[6] + sr[7] * sc[7] + sr[8] * sc[8];
    uint4 t0 = make_uint4(packbf(d2, ip0), packbf(ip1, ip2), 0, 0);
    uint4 z = make_uint4(0, 0, 0, 0);
    *(uint4*)(tailb + (size_t)e * 16) = t0;
    *(uint4*)(tailb + (size_t)e * 16 + 8) = z;
}

// gather p/s aggregation: one wave per node
__global__ void k_gather_ps(const int* __restrict__ ptr, const int* __restrict__ col_s,
                            const float* __restrict__ pos, const float* __restrict__ sh,
                            const float* __restrict__ psc, const float* __restrict__ ssc,
                            float* __restrict__ p_sum, float* __restrict__ s_sum) {
    int n = blockIdx.x;
    int lane = threadIdx.x;  // 64
    int s0 = ptr[n], s1 = ptr[n + 1];
    float px = pos[n * 3 + 0], py = pos[n * 3 + 1], pz = pos[n * 3 + 2];
    float shn[9];
#pragma unroll
    for (int j = 0; j < 9; j++) shn[j] = sh[(size_t)n * 9 + j];
    float a[12];
#pragma unroll
    for (int j = 0; j < 12; j++) a[j] = 0.0f;
    for (int e = s0 + lane; e < s1; e += 64) {
        int c = col_s[e];
        float p = psc[e];
        a[0] += (px - pos[c * 3 + 0]) * p;
        a[1] += (py - pos[c * 3 + 1]) * p;
        a[2] += (pz - pos[c * 3 + 2]) * p;
        float w0 = ssc[e * 3 + 0], w1 = ssc[e * 3 + 1], w2 = ssc[e * 3 + 2];
        const float* sc = sh + (size_t)c * 9;
        a[3]  += (shn[0] - sc[0]) * w0;
        a[4]  += (shn[1] - sc[1]) * w1;
        a[5]  += (shn[2] - sc[2]) * w1;
        a[6]  += (shn[3] - sc[3]) * w1;
        a[7]  += (shn[4] - sc[4]) * w2;
        a[8]  += (shn[5] - sc[5]) * w2;
        a[9]  += (shn[6] - sc[6]) * w2;
        a[10] += (shn[7] - sc[7]) * w2;
        a[11] += (shn[8] - sc[8]) * w2;
    }
#pragma unroll
    for (int off = 32; off > 0; off >>= 1)
#pragma unroll
        for (int j = 0; j < 12; j++) a[j] += __shfl_down(a[j], off, 64);
    if (lane == 0) {
        float cinv = 1.0f / fmaxf((float)(s1 - s0), 1.0f);
#pragma unroll
        for (int j = 0; j < 3; j++) p_sum[(size_t)n * 3 + j] = a[j] * cinv;
#pragma unroll
        for (int j = 0; j < 9; j++) s_sum[(size_t)n * 9 + j] = a[3 + j] * cinv;
    }
}

__global__ void k_update_nodes(float* __restrict__ sh, float* __restrict__ pos,
                               const float* __restrict__ s_sum, const float* __restrict__ p_sum) {
    int n = blockIdx.x * blockDim.x + threadIdx.x;
    if (n >= NA) return;
#pragma unroll
    for (int j = 0; j < 9; j++) sh[n * 9 + j] += s_sum[(size_t)n * 9 + j];
#pragma unroll
    for (int j = 0; j < 3; j++) pos[n * 3 + j] += p_sum[(size_t)n * 3 + j];
}

// gather m-mean + build Xn: one block(128) per node
__global__ __launch_bounds__(128) void k_gather_xn(
    const int* __restrict__ ptr, const unsigned short* __restrict__ bufMb,
    const unsigned short* __restrict__ featb, unsigned short* __restrict__ Xnb) {
    int n = blockIdx.x;
    int c = threadIdx.x;  // 128
    int s0 = ptr[n], s1 = ptr[n + 1];
    float sum = 0.0f;
    for (int e = s0; e < s1; e++) sum += bf2f(bufMb[(size_t)e * 128 + c]);
    float cinv = 1.0f / fmaxf((float)(s1 - s0), 1.0f);
    Xnb[(size_t)n * 256 + c] = featb[(size_t)n * 128 + c];
    Xnb[(size_t)n * 256 + 128 + c] = f2bf(sum * cinv);
}

// fused pool (segment_sum) + prediction
__global__ __launch_bounds__(192) void k_pool_pred(
    const int* __restrict__ gptr, const float* __restrict__ feat,
    const float* __restrict__ pos, const float* __restrict__ sh,
    const float* __restrict__ Wp, const float* __restrict__ bp,
    float* __restrict__ out) {
    __shared__ float pl[140];
    int g = blockIdx.x;
    int c = threadIdx.x;
    int s0 = gptr[g], s1 = gptr[g + 1];
    if (c < 140) {
        float sum = 0.0f;
        for (int n = s0; n < s1; n++) {
            float v;
            if (c < 128)      v = feat[(size_t)n * 128 + c];
            else if (c < 131) v = pos[n * 3 + (c - 128)];
            else              v = sh[(size_t)n * 9 + (c - 131)];
            sum += v;
        }
        pl[c] = sum;
    }
    __syncthreads();
    if (c < 64) {
        float s = 0.0f;
        for (int k = c; k < 140; k += 64) s += pl[k] * Wp[k];
#pragma unroll
        for (int off = 32; off > 0; off >>= 1) s += __shfl_down(s, off, 64);
        if (c == 0) out[g] = s + bp[0];
    }
}

// ---------------------------------------------------------------------------
extern "C" void kernel_launch(void* const* d_in, const int* in_sizes, int n_in,
                              void* d_out, int out_size, void* d_ws, size_t ws_size,
                              hipStream_t stream) {
    const int*   atoms  = (const int*)d_in[0];
    const int*   eidx   = (const int*)d_in[1];
    const int*   row    = eidx;
    const int*   col    = eidx + NE;
    const int*   bid    = (const int*)d_in[2];
    const float* pos_in = (const float*)d_in[3];
    const float* emb    = (const float*)d_in[4];
    const float* Wsi1   = (const float*)d_in[5];
    const float* bsi1   = (const float*)d_in[6];
    const float* Wsi2   = (const float*)d_in[7];
    const float* bsi2   = (const float*)d_in[8];
    const float* WsiC1  = (const float*)d_in[9];
    const float* bsiC1  = (const float*)d_in[10];
    const float* WsiC2  = (const float*)d_in[11];
    const float* bsiC2  = (const float*)d_in[12];
    const float* Wm1    = (const float*)d_in[13];
    const float* bm1    = (const float*)d_in[14];
    const float* Wm2    = (const float*)d_in[15];
    const float* bm2    = (const float*)d_in[16];
    const float* Wp1    = (const float*)d_in[17];
    const float* bp1    = (const float*)d_in[18];
    const float* Wp2    = (const float*)d_in[19];
    const float* bp2    = (const float*)d_in[20];
    const float* Wn1    = (const float*)d_in[21];
    const float* bn1    = (const float*)d_in[22];
    const float* Wn2    = (const float*)d_in[23];
    const float* bn2    = (const float*)d_in[24];
    const float* Ws1    = (const float*)d_in[25];
    const float* bs1    = (const float*)d_in[26];
    const float* Ws2    = (const float*)d_in[27];
    const float* bs2    = (const float*)d_in[28];
    const float* Wpred  = (const float*)d_in[29];
    const float* bpred  = (const float*)d_in[30];

    float* base = (float*)d_ws;
    size_t off = 0;
    auto alloc = [&](size_t nfl) { float* r = base + off; off += nfl; return r; };
    unsigned short* bufHb = (unsigned short*)alloc((size_t)NE * DF / 2);
    unsigned short* bufMb = (unsigned short*)alloc((size_t)NE * DF / 2);
    unsigned short* featb = (unsigned short*)alloc((size_t)NAP * DF / 2);
    unsigned short* hnb   = (unsigned short*)alloc((size_t)NAP * DF / 2);
    unsigned short* Xnb   = (unsigned short*)alloc((size_t)NAP * 256 / 2);
    unsigned short* tailb = (unsigned short*)alloc((size_t)NE * 16 / 2);
    unsigned short* WT    = (unsigned short*)alloc(WT_TOTAL / 2);
    float* feat    = alloc((size_t)NAP * DF);
    float* sc3     = alloc((size_t)NE * 3);
    float* psc     = alloc(NE);
    float* posc    = alloc((size_t)NA * 3 + 4);
    float* sh      = alloc((size_t)NA * 9 + 4);
    float* p_sum   = alloc((size_t)NA * 3 + 4);
    float* s_sum   = alloc((size_t)NA * 9 + 4);
    float* sh_mean = alloc((size_t)NA * 9 + 4);
    float* com     = alloc(NG * 3 + 4);
    float* msgC    = alloc((size_t)NA * 3 + 4);
    int* cnt_row   = (int*)alloc(NA);
    int* ptr       = (int*)alloc(NA + 4);
    int* cursor    = (int*)alloc(NA);
    int* gptr      = (int*)alloc(NG + 4);
    int* row_s     = (int*)alloc(NE);
    int* col_s     = (int*)alloc(NE);
    int* btot      = (int*)alloc(64);

    const dim3 B256(256);
    const int gE = NE / 128;                    // 1250
    const int gN = NAP / 128;                   // 79

    // ---------- setup: weights, sort, graph ranges ----------
    hipMemsetAsync(cnt_row, 0, NA * sizeof(int), stream);
    k_prep_w<<<(WT_TOTAL + 255) / 256, B256, 0, stream>>>(Wsi1, WsiC1, Wm1, Wm2, Wp1, Ws1, Wn1, Wn2, WT);
    k_init_feat<<<(NA * DF + 255) / 256, B256, 0, stream>>>(atoms, emb, feat, featb);
    k_copy_pos<<<(NA * 3 + 255) / 256, B256, 0, stream>>>(pos_in, posc);
    k_count_edges<<<(NE + 255) / 256, B256, 0, stream>>>(row, cnt_row);
    k_scan_block<<<NSB, B256, 0, stream>>>(cnt_row, ptr, btot);
    k_scan_tot<<<1, 64, 0, stream>>>(btot);
    k_scan_add<<<NSB, B256, 0, stream>>>(ptr, btot);
    k_copy_cursor<<<NSB, B256, 0, stream>>>(ptr, cursor);
    k_sort<<<(NE + 255) / 256, B256, 0, stream>>>(row, col, cursor, row_s, col_s);
    k_gptr<<<(NA + 255) / 256, B256, 0, stream>>>(bid, gptr);
    k_com_g<<<NG, 64, 0, stream>>>(pos_in, gptr, com);

    // ---------- initial sh ----------
    k_tail_init<<<(NE + 255) / 256, B256, 0, stream>>>(row_s, col_s, posc, tailb);
    gemm_mfma<288, 1, true, 3, false><<<gE, B256, 0, stream>>>(
        nullptr, WT + OFF_SI1, bsi1, nullptr, nullptr, NE, row_s, col_s, featb, tailb,
        Wsi2, bsi2, sc3);
    k_gather_sph<<<NA, 64, 0, stream>>>(ptr, col_s, posc, sc3, sh_mean);
    gemm_mfma<128, 0, true, 3, false><<<gN, B256, 0, stream>>>(
        featb, WT + OFF_SIC1, bsiC1, nullptr, nullptr, NA, nullptr, nullptr, nullptr, nullptr,
        WsiC2, bsiC2, msgC);
    k_sh_finish<<<(NA + 255) / 256, B256, 0, stream>>>(sh_mean, posc, com, bid, msgC, sh);

    // ---------- layers ----------
    for (int l = 0; l < NL; l++) {
        const unsigned short* wtL = WT + LBASE + (size_t)l * LSIZE;
        const float* cm1 = bm1 + l * 128;
        const float* cm2 = bm2 + l * 128;
        const float* cp1 = bp1 + l * 128;
        const float* wp2 = Wp2 + (size_t)l * 128;
        const float* cp2 = bp2 + l;
        const float* cn1 = bn1 + l * 128;
        const float* cn2 = bn2 + l * 128;
        const float* cs1 = bs1 + l * 128;
        const float* ws2 = Ws2 + (size_t)l * 128 * 3;
        const float* cs2 = bs2 + l * 3;

        k_edge_pre<<<(NE + 255) / 256, B256, 0, stream>>>(row_s, col_s, posc, sh, tailb);
        gemm_mfma<288, 1, true, 0, false><<<gE, B256, 0, stream>>>(
            nullptr, wtL + LOFF_M1, cm1, bufHb, nullptr, NE, row_s, col_s, featb, tailb,
            nullptr, nullptr, nullptr);
        gemm_mfma<128, 0, true, 0, false><<<gE, B256, 0, stream>>>(
            bufHb, wtL + LOFF_M2, cm2, bufMb, nullptr, NE, nullptr, nullptr, nullptr, nullptr,
            nullptr, nullptr, nullptr);
        gemm_mfma<128, 0, true, 1, false><<<gE, B256, 0, stream>>>(
            bufMb, wtL + LOFF_P1, cp1, nullptr, nullptr, NE, nullptr, nullptr, nullptr, nullptr,
            wp2, cp2, psc);
        gemm_mfma<128, 0, true, 3, false><<<gE, B256, 0, stream>>>(
            bufMb, wtL + LOFF_S1, cs1, nullptr, nullptr, NE, nullptr, nullptr, nullptr, nullptr,
            ws2, cs2, sc3);

        k_gather_ps<<<NA, 64, 0, stream>>>(ptr, col_s, posc, sh, psc, sc3, p_sum, s_sum);
        k_update_nodes<<<(NA + 255) / 256, B256, 0, stream>>>(sh, posc, s_sum, p_sum);
        k_gather_xn<<<NA, 128, 0, stream>>>(ptr, bufMb, featb, Xnb);
        gemm_mfma<256, 0, true, 0, false><<<gN, B256, 0, stream>>>(
            Xnb, wtL + LOFF_N1, cn1, hnb, nullptr, NA, nullptr, nullptr, nullptr, nullptr,
            nullptr, nullptr, nullptr);
        gemm_mfma<128, 0, false, 0, true><<<gN, B256, 0, stream>>>(
            hnb, wtL + LOFF_N2, cn2, featb, feat, NA, nullptr, nullptr, nullptr, nullptr,
            nullptr, nullptr, nullptr);
    }

    // ---------- pooling + prediction ----------
    k_pool_pred<<<NG, 192, 0, stream>>>(gptr, feat, posc, sh, Wpred, bpred, (float*)d_out);
}